// Round 9
// baseline (720.767 us; speedup 1.0000x reference)
//
#include <hip/hip_runtime.h>

// PinkNet: x(512,24,24,10,1) -T-> (B,1,T,Y,X) -conv1(dil 2,2)-> relu -> *mask
//          -conv2-> -T-> out.
// r30: conv2 = r26 body + kt-zero skip (scalar-guarded). CORRECTED FLOOR
//      ARITHMETIC: conv2 FMA issue = 212M wave-inst = 172us floor -> r26's
//      274us is 63% of floor; r25/r27/r28/r29 all failed because they never
//      cut FMAs. This round: ot-groups with kt=tp-ot+7 outside [0,10) have
//      exactly-zero weights (k_wz builds them as 0) -> skip 4 FMAs + 4
//      weight s_loads per such group via wave-uniform scalar branch on
//      tp=meta/280 (readfirstlane -> SGPR). 31% fewer FMAs (floor 119us) and
//      31% fewer scalar weight bytes. Numerically identical (skipped terms
//      are fmaf(+0,xv,acc)). wz4 dropped (r29 FETCH regression); plain wz.
//      conv1m = r22 (global_load_lds dbuf MFMA). Others unchanged.
//
// ws ints @0: bitmap[2304], off[2304]@2304, basep[4]@4608, cellmeta[5760]@5120
// floats: mval[5760] @14336 ; FBASE=20480:
//   [FBASE..FBASE+4P)  part (conv2 out). conv1-only aliases (11.67M < 4P):
//     xbh @+0 (1572864 fl), xbl @+1572864, w1mh @+3145728 (1310720 fl),
//     w1ml @+4456448
//   [FBASE+4P..FBASE+5P) h1c[5760][512] fp32
//   [FBASE+5P..]         wz[224000]

#define NSLOT 5760
static constexpr int P     = 10 * 24 * 24 * 512;     // 2,949,120 = NSLOT*512
static constexpr int FBASE = 20480;
static constexpr int WZN   = 4 * 20 * 10 * 10 * 28;  // 224,000
static constexpr int W1SN  = 2 * 4 * 20 * 4 * 128 * 32; // 2,621,440 ushorts
static constexpr int XBT   = 24 * 4 * 512 * 32;      // per-parity xb elems

using bf16x8 = __attribute__((ext_vector_type(8))) short;  // 4 VGPRs
using f32x4  = __attribute__((ext_vector_type(4))) float;

__device__ __forceinline__ unsigned short f2bf(float f) {  // RNE float->bf16
  unsigned u = __float_as_uint(f);
  u += 0x7fff + ((u >> 16) & 1);
  return (unsigned short)(u >> 16);
}
__device__ __forceinline__ float bf2f(unsigned short h) {
  return __uint_as_float((unsigned)h << 16);
}

__device__ __forceinline__ void gload16(const void* g, void* l) {
  __builtin_amdgcn_global_load_lds(
      (const __attribute__((address_space(1))) unsigned int*)g,
      (__attribute__((address_space(3))) unsigned int*)l, 16, 0, 0);
}

// -- kernel 1: x[b][ix][y][t] -> xb{E,O}_{hi,lo}[p][y][ks][b][kk] (k-sliced) --
__global__ __launch_bounds__(256) void k_xbt(const float* __restrict__ x,
                                             unsigned short* __restrict__ xbh,
                                             unsigned short* __restrict__ xbl) {
  __shared__ float lds[64][241];
  const int ix = blockIdx.x;               // 0..23
  const int b0 = blockIdx.y * 64;
  const int tid = threadIdx.x;
  const int p = ix & 1;                    // parity table
  const int c0 = (ix >> 1) * 10;           // column base within table
  #pragma unroll 4
  for (int i = 0; i < 60; ++i) {
    int idx = i * 256 + tid;
    int yt = idx % 240, lb = idx / 240;    // contiguous reads
    lds[lb][yt] = x[(size_t)(b0 + lb) * 5760 + ix * 240 + yt];
  }
  __syncthreads();
  #pragma unroll
  for (int i = 0; i < 6; ++i) {
    int q = i * 256 + tid;
    int lb = q & 63, y = q >> 6;           // y in [0,24)
    const int b = b0 + lb;
    const float* src = &lds[lb][y * 10];
    #pragma unroll
    for (int k0 = 0; k0 < 10; ++k0) {
      const int k = c0 + k0;
      const int ks = k >> 5, kk = k & 31;
      const size_t a = (size_t)p * XBT +
                       (((size_t)(y * 4 + ks) * 512 + b) * 32 + kk);
      float f = src[k0];
      unsigned short hh = f2bf(f);
      xbh[a] = hh;
      xbl[a] = f2bf(f - bf2f(hh));
    }
    if (ix < 2) {                          // zero tail cols 120..127 (k-pad)
      #pragma unroll
      for (int k = 120; k < 128; ++k) {
        const size_t a = (size_t)p * XBT +
                         (((size_t)(y * 4 + 3) * 512 + b) * 32 + (k & 31));
        xbh[a] = 0; xbl[a] = 0;
      }
    }
  }
}

// --- kernel 2: per-(typ,pos) t-bitmaps, prefix offsets, cell metadata ---
__global__ __launch_bounds__(256) void k_meta(const float* __restrict__ mask,
                                              int* __restrict__ bitmap,
                                              int* __restrict__ off,
                                              int* __restrict__ basep,
                                              int* __restrict__ cellmeta,
                                              float* __restrict__ mval) {
  __shared__ int tot[4];
  __shared__ int sb[4];
  const int tid = threadIdx.x;
  const int typ = tid >> 6, lane = tid & 63;       // one wave per typ
  int running = 0;
  for (int c = 0; c < 9; ++c) {                    // 9*64 = 576 positions
    const int pos = c * 64 + lane;
    int mb = 0;
    #pragma unroll
    for (int t = 0; t < 10; ++t)
      if (mask[typ * 5760 + t * 576 + pos] != 0.0f) mb |= (1 << t);
    bitmap[typ * 576 + pos] = mb;
    const int cnt = __popc(mb);
    int s = cnt;                                   // inclusive wave scan
    #pragma unroll
    for (int o = 1; o < 64; o <<= 1) {
      int v = __shfl_up(s, o, 64);
      if (lane >= o) s += v;
    }
    off[typ * 576 + pos] = running + s - cnt;      // exclusive, within typ
    running += __shfl(s, 63, 64);
  }
  if (lane == 63) tot[typ] = running;
  __syncthreads();
  if (tid == 0) {
    int a = 0;
    for (int q = 0; q < 4; ++q) { basep[q] = a; sb[q] = a; a += tot[q]; }
  }
  __syncthreads();
  for (int c = 0; c < 9; ++c) {
    const int pos = c * 64 + lane;
    const int mb = bitmap[typ * 576 + pos];
    int o = sb[typ] + off[typ * 576 + pos];
    const int ex = pos % 24;
    #pragma unroll
    for (int tp = 0; tp < 10; ++tp)
      if ((mb >> tp) & 1) {
        cellmeta[o] = tp * 280 + ex;
        mval[o] = mask[typ * 5760 + tp * 576 + pos];
        ++o;
      }
  }
}

// ---- kernel 2b: wz[typ][ky][tp][ot][c] zero-padded conv2 weights ----
__global__ __launch_bounds__(256) void k_wz(const float* __restrict__ w2,
                                            float* __restrict__ wz) {
  int idx = blockIdx.x * 256 + threadIdx.x;
  if (idx >= WZN) return;
  int c = idx % 28; int r = idx / 28;
  int ot = r % 10; r /= 10;
  int tp = r % 10; r /= 10;
  int ky = r % 20; int typ = r / 20;
  int kt = tp - ot + 7;
  float v = 0.0f;
  if (kt >= 0 && kt < 10 && c >= 3 && c <= 22)
    v = w2[typ * 4000 + kt * 400 + ky * 20 + (c - 3)];
  wz[idx] = v;
}

// -- kernel 2c: w1s_{hi,lo}[h][typ][ky][ks][r][kk] k-sliced im2col tables --
// h=0: ox odd, xx even; h=1: ox even, xx odd. r=(ox>>1)*10+ot, k=(xx>>1)*10+t
__global__ __launch_bounds__(256) void k_w1m(const float* __restrict__ w1,
                                             unsigned short* __restrict__ w1mh,
                                             unsigned short* __restrict__ w1ml) {
  int idx = blockIdx.x * 256 + threadIdx.x;
  if (idx >= W1SN) return;
  int kk = idx & 31;
  int r = (idx >> 5) & 127;
  int rest = idx >> 12;
  int ks = rest & 3; rest >>= 2;
  int ky = rest % 20; rest /= 20;
  int typ = rest % 4; int h = rest / 4;
  int c = ks * 32 + kk;
  float v = 0.0f;
  if (r < 120 && c < 120) {
    int ox = 2 * (r / 10) + (h == 0 ? 1 : 0);
    int ot = r % 10;
    int xx = 2 * (c / 10) + (h == 0 ? 0 : 1);
    int t  = c % 10;
    int sx = xx - ox + 19;                 // even by parity construction
    int kt = t - ot + 7;
    if (sx >= 0 && sx <= 38 && (unsigned)kt <= 9u)
      v = w1[typ * 4000 + kt * 400 + ky * 20 + (sx >> 1)];
  }
  unsigned short h16 = f2bf(v);
  w1mh[idx] = h16;
  w1ml[idx] = f2bf(v - bf2f(h16));
}

// -- kernel 3: conv1 MFMA, m97-style: global_load_lds dbuf staging, 1 h/block
__global__ __launch_bounds__(256) void k_conv1m(
    const unsigned short* __restrict__ xbh,   // [2][24][4][512][32]
    const unsigned short* __restrict__ xbl,
    const unsigned short* __restrict__ w1mh,  // [2][4][20][4][128][32]
    const unsigned short* __restrict__ w1ml,
    const int* __restrict__ bitmap, const int* __restrict__ off,
    const int* __restrict__ basep, const float* __restrict__ mval,
    float* __restrict__ h1c) {
  __shared__ unsigned short lds[2][12288];   // 2 x 24 KiB
  const int lin = blockIdx.x;                // 0..1535
  const int cx = lin & 7;                    // XCD (round-robin assumed)
  const int typ = cx >> 1, half = cx & 1;
  const int i = lin >> 3;                    // 0..191
  const int n0 = (i & 7) * 64;               // n-strip innermost
  const int rest = i >> 3;                   // 0..23
  const int h = rest & 1;                    // parity half: 0=odd-ox, 1=even
  const int oy = half * 12 + (rest >> 1);
  const int w = threadIdx.x >> 6;            // wave 0..3 -> M tiles w*2,w*2+1
  const int lane = threadIdx.x & 63;
  const int l15 = lane & 15;
  const int kg = (lane >> 4) * 8;            // k sub-offset within 32

  // valid same-parity yy range: sy = yy-oy+19 in [0,38]
  const int py = (oy + 1) & 1;
  int ylo = oy - 19; if (ylo < 0) ylo = 0;
  ylo += (ylo & 1) ^ py;
  int yhi = oy + 19; if (yhi > 23) yhi = 23;
  yhi -= (yhi & 1) ^ py;
  const int ns = (((yhi - ylo) >> 1) + 1) * 4;   // 4 k-slices per yy

  f32x4 acc[2][4];
  #pragma unroll
  for (int mi = 0; mi < 2; ++mi)
    #pragma unroll
    for (int nt = 0; nt < 4; ++nt) {
      f32x4 z = {0.f, 0.f, 0.f, 0.f};
      acc[mi][nt] = z;
    }

  auto stage = [&](int s, int bufi) {
    const int yy = ylo + ((s >> 2) << 1);
    const int ks = s & 3;
    const int ky = (yy - oy + 19) >> 1;
    const size_t asl = ((size_t)((h * 4 + typ) * 20 + ky) * 4 + ks) << 12;
    const unsigned short* Ah = w1mh + asl;
    const unsigned short* Al = w1ml + asl;
    const size_t bsl = (((size_t)(h * 24 + yy) * 4 + ks) << 14) +
                       (size_t)n0 * 32;
    const unsigned short* Bh = xbh + bsl;
    const unsigned short* Bl = xbl + bsl;
    char* lb = (char*)&lds[bufi][0];
    #pragma unroll
    for (int ia = 0; ia < 2; ++ia) {          // A: 8192 B per table
      const int L = ia * 4096 + w * 1024 + lane * 16;
      const int row = L >> 6;
      const int g = row * 64 + ((((L >> 4) & 3) ^ ((row >> 1) & 3)) << 4);
      gload16((const char*)Ah + g, lb + ia * 4096 + w * 1024);
      gload16((const char*)Al + g, lb + 8192 + ia * 4096 + w * 1024);
    }
    {                                          // B: 4096 B per table
      const int L = w * 1024 + lane * 16;
      const int row = L >> 6;
      const int g = row * 64 + ((((L >> 4) & 3) ^ ((row >> 1) & 3)) << 4);
      gload16((const char*)Bh + g, lb + 16384 + w * 1024);
      gload16((const char*)Bl + g, lb + 20480 + w * 1024);
    }
  };

  stage(0, 0);
  __syncthreads();
  int cur = 0;
  for (int s = 0; s < ns; ++s) {
    if (s + 1 < ns) stage(s + 1, cur ^ 1);     // issue next-slice loads first
    const unsigned short* bufb = &lds[cur][0];
    bf16x8 bhv[4], blv[4];
    #pragma unroll
    for (int nt = 0; nt < 4; ++nt) {
      const int n = nt * 16 + l15;
      const int by = n * 64 + (((kg >> 3) ^ ((n >> 1) & 3)) << 4);
      bhv[nt] = *(const bf16x8*)((const char*)(bufb + 8192) + by);
      blv[nt] = *(const bf16x8*)((const char*)(bufb + 10240) + by);
    }
    #pragma unroll
    for (int mi = 0; mi < 2; ++mi) {
      const int r = (w * 2 + mi) * 16 + l15;
      const int ay = r * 64 + (((kg >> 3) ^ ((r >> 1) & 3)) << 4);
      const bf16x8 ah = *(const bf16x8*)((const char*)bufb + ay);
      const bf16x8 al = *(const bf16x8*)((const char*)(bufb + 4096) + ay);
      #pragma unroll
      for (int nt = 0; nt < 4; ++nt) {
        acc[mi][nt] = __builtin_amdgcn_mfma_f32_16x16x32_bf16(
            al, blv[nt], acc[mi][nt], 0, 0, 0);
        acc[mi][nt] = __builtin_amdgcn_mfma_f32_16x16x32_bf16(
            ah, blv[nt], acc[mi][nt], 0, 0, 0);
        acc[mi][nt] = __builtin_amdgcn_mfma_f32_16x16x32_bf16(
            al, bhv[nt], acc[mi][nt], 0, 0, 0);
        acc[mi][nt] = __builtin_amdgcn_mfma_f32_16x16x32_bf16(
            ah, bhv[nt], acc[mi][nt], 0, 0, 0);
      }
    }
    __syncthreads();                           // drain staging + ds reads
    cur ^= 1;
  }

  // epilogue: compact write with fused relu * mval -> h1c (final values)
  const int bo = basep[typ];
  #pragma unroll
  for (int mi = 0; mi < 2; ++mi) {
    #pragma unroll
    for (int reg = 0; reg < 4; ++reg) {
      const int r = (w * 2 + mi) * 16 + (lane >> 4) * 4 + reg;
      if (r >= 120) continue;                  // padded rows
      const int ox = 2 * (r / 10) + (h == 0 ? 1 : 0);
      const int ot = r % 10;
      const int pos = oy * 24 + ox;
      const int mb = bitmap[typ * 576 + pos];
      if ((mb >> ot) & 1) {
        const int slot = bo + off[typ * 576 + pos] +
                         __popc(mb & ((1 << ot) - 1));
        const float mv = mval[slot];
        #pragma unroll
        for (int nt = 0; nt < 4; ++nt)
          h1c[(size_t)slot * 512 + n0 + nt * 16 + l15] =
              fmaxf(acc[mi][nt][reg], 0.0f) * mv;
      }
    }
  }
}

// -- kernel 4: conv2 (r30 = r26 + kt-zero skip). Per slot, tp = meta/280 is
// wave-uniform; ot groups with kt=tp-ot+7 outside [0,10) have exactly-zero
// weights -> scalar-branch skip of 4 FMAs + 4 weight loads per group
// (31% of total). Depth-4 meta/xv hoisting, r26 grid/order.
__global__ __launch_bounds__(256) void k_conv2(const float* __restrict__ h1c,
                                               const float* __restrict__ wz,
                                               const int* __restrict__ bitmap,
                                               const int* __restrict__ off,
                                               const int* __restrict__ basep,
                                               const int* __restrict__ cellmeta,
                                               float* __restrict__ part) {
  const int lin = blockIdx.x;
  const int cx = lin & 7, i = lin >> 3;
  const int typ = cx >> 1;
  const int oy  = (cx & 1) * 12 + (i % 12);
  const int x12 = i / 12;
  const int tile = x12 >> 1, bh = x12 & 1;
  const int ox0 = tile * 4;
  const int b = bh * 256 + threadIdx.x;
  const int bo = __builtin_amdgcn_readfirstlane(basep[typ]);

  float acc[40];
  #pragma unroll
  for (int i2 = 0; i2 < 40; ++i2) acc[i2] = 0.0f;

  const int ex_lo = ox0 - 10 < 0 ? 0 : ox0 - 10;   // d = ex-ox0+10 in [0,22]
  const int ex_hi = ox0 + 12 > 23 ? 23 : ox0 + 12;
  const int ey0 = oy - 10 < 0 ? 0 : oy - 10;
  const int ey1 = oy + 9 > 23 ? 23 : oy + 9;

  auto fmablock = [&](int meta, float xv, int rbase) {
    const int tp = meta / 280;                 // wave-uniform (meta scalar)
    const float* wrow = wz + rbase + meta;
    #pragma unroll
    for (int ot = 0; ot < 10; ++ot) {
      if (ot >= tp - 2 && ot <= tp + 7) {      // kt in [0,9]; else w == +0.0
        #pragma unroll
        for (int j = 0; j < 4; ++j)
          acc[ot * 4 + j] = fmaf(wrow[ot * 28 + 3 - j], xv, acc[ot * 4 + j]);
      }
    }
  };

  for (int ey = ey0; ey <= ey1; ++ey) {
    const int ky = ey - oy + 10;
    const int rowb = typ * 576 + ey * 24;
    const int s_lo = bo + __builtin_amdgcn_readfirstlane(off[rowb + ex_lo]);
    const int s_hi = bo + __builtin_amdgcn_readfirstlane(off[rowb + ex_hi]) +
                     __popc(__builtin_amdgcn_readfirstlane(bitmap[rowb + ex_hi]));
    const int rbase = (typ * 20 + ky) * 2800 + 10 - ox0;
    int s = s_lo;
    for (; s + 4 <= s_hi; s += 4) {                // depth-4: hoist meta+xv
      const int m0 = __builtin_amdgcn_readfirstlane(cellmeta[s]);
      const int m1 = __builtin_amdgcn_readfirstlane(cellmeta[s + 1]);
      const int m2 = __builtin_amdgcn_readfirstlane(cellmeta[s + 2]);
      const int m3 = __builtin_amdgcn_readfirstlane(cellmeta[s + 3]);
      const float xv0 = h1c[(size_t)s * 512 + b];
      const float xv1 = h1c[(size_t)(s + 1) * 512 + b];
      const float xv2 = h1c[(size_t)(s + 2) * 512 + b];
      const float xv3 = h1c[(size_t)(s + 3) * 512 + b];
      fmablock(m0, xv0, rbase);
      fmablock(m1, xv1, rbase);
      fmablock(m2, xv2, rbase);
      fmablock(m3, xv3, rbase);
    }
    if (s + 2 <= s_hi) {                           // depth-2
      const int m0 = __builtin_amdgcn_readfirstlane(cellmeta[s]);
      const int m1 = __builtin_amdgcn_readfirstlane(cellmeta[s + 1]);
      const float xv0 = h1c[(size_t)s * 512 + b];
      const float xv1 = h1c[(size_t)(s + 1) * 512 + b];
      fmablock(m0, xv0, rbase);
      fmablock(m1, xv1, rbase);
      s += 2;
    }
    if (s < s_hi) {                                // tail
      const int m0 = __builtin_amdgcn_readfirstlane(cellmeta[s]);
      const float xv0 = h1c[(size_t)s * 512 + b];
      fmablock(m0, xv0, rbase);
    }
  }
  #pragma unroll
  for (int ot = 0; ot < 10; ++ot)
    #pragma unroll
    for (int j = 0; j < 4; ++j)
      part[(size_t)(((typ * 10 + ot) * 24 + oy) * 24 + ox0 + j) * 512 + b] =
          acc[ot * 4 + j];
}

// ------ kernel 5: sum 4 typ-partials + transpose to out[b][x][y][t] ------
__global__ __launch_bounds__(256) void k_reduce(const float* __restrict__ part,
                                                float* __restrict__ out) {
  __shared__ float lds[64][241];
  const int xb = blockIdx.x;
  const int b0 = blockIdx.y * 64;
  const int tid = threadIdx.x;
  #pragma unroll 4
  for (int i = 0; i < 60; ++i) {
    int idx = i * 256 + tid;
    int yt = idx >> 6, lb = idx & 63;
    int y = yt / 10, t = yt % 10;
    size_t a = (size_t)((t * 24 + y) * 24 + xb) * 512 + b0 + lb;
    lds[lb][yt] = part[a] + part[a + P] + part[a + 2 * (size_t)P] +
                  part[a + 3 * (size_t)P];
  }
  __syncthreads();
  #pragma unroll 4
  for (int i = 0; i < 60; ++i) {
    int idx = i * 256 + tid;
    int yt = idx % 240, lb = idx / 240;
    out[(size_t)(b0 + lb) * 5760 + xb * 240 + yt] = lds[lb][yt];
  }
}

extern "C" void kernel_launch(void* const* d_in, const int* in_sizes, int n_in,
                              void* d_out, int out_size, void* d_ws, size_t ws_size,
                              hipStream_t stream) {
  const float* x    = (const float*)d_in[0];
  const float* w1   = (const float*)d_in[1];
  const float* w2   = (const float*)d_in[2];
  const float* mask = (const float*)d_in[3];
  float* out = (float*)d_out;
  float* wsf = (float*)d_ws;

  int* bitmap   = (int*)d_ws;
  int* off      = bitmap + 2304;
  int* basep    = bitmap + 4608;
  int* cellmeta = bitmap + 5120;
  float* mval   = wsf + 14336;
  float* part = wsf + FBASE;                             // conv2 out
  unsigned short* xbh  = (unsigned short*)(wsf + FBASE);               // conv1
  unsigned short* xbl  = (unsigned short*)(wsf + FBASE + 1572864);     // conv1
  unsigned short* w1mh = (unsigned short*)(wsf + FBASE + 3145728);     // conv1
  unsigned short* w1ml = (unsigned short*)(wsf + FBASE + 4456448);     // conv1
  float* h1c = wsf + FBASE + (size_t)4 * P;
  float* wz  = wsf + FBASE + (size_t)5 * P;

  k_meta<<<1, 256, 0, stream>>>(mask, bitmap, off, basep, cellmeta, mval);
  k_wz<<<(WZN + 255) / 256, 256, 0, stream>>>(w2, wz);
  k_w1m<<<(W1SN + 255) / 256, 256, 0, stream>>>(w1, w1mh, w1ml);
  k_xbt<<<dim3(24, 8), 256, 0, stream>>>(x, xbh, xbl);
  k_conv1m<<<1536, 256, 0, stream>>>(xbh, xbl, w1mh, w1ml,
                                     bitmap, off, basep, mval, h1c);
  k_conv2<<<1152, 256, 0, stream>>>(h1c, wz, bitmap, off, basep,
                                    cellmeta, part);
  k_reduce<<<dim3(24, 8), 256, 0, stream>>>(part, out);
}

// Round 10
// 422.482 us; speedup vs baseline: 1.7060x; 1.7060x over previous
//
#include <hip/hip_runtime.h>

// PinkNet: x(512,24,24,10,1) -T-> (B,1,T,Y,X) -conv1(dil 2,2)-> relu -> *mask
//          -conv2-> -T-> out.
// r31: conv2 REVERTED to r26 verbatim (best measured: 274us; r27/r28/r29/r30
//      all regressed -> r26's straight-line SGPR-weight body is ~80% of its
//      practical floor; stop touching it). conv1m: drop the al*bl MFMA
//      product (low x low split term, <= 2^-16 relative ~ 1.5e-5 per term):
//      32 -> 24 MFMA per k-slice (-25% MFMA issue), staging/structure
//      unchanged. Numerics shift in low-order bits only (absmax ~0.03 vs
//      0.299 threshold). Others unchanged from r26.
//
// ws ints @0: bitmap[2304], off[2304]@2304, basep[4]@4608, cellmeta[5760]@5120
// floats: mval[5760] @14336 ; FBASE=20480:
//   [FBASE..FBASE+4P)  part (conv2 out). conv1-only aliases (11.67M < 4P):
//     xbh @+0 (1572864 fl), xbl @+1572864, w1mh @+3145728 (1310720 fl),
//     w1ml @+4456448
//   [FBASE+4P..FBASE+5P) h1c[5760][512] fp32
//   [FBASE+5P..]         wz[224000]

#define NSLOT 5760
static constexpr int P     = 10 * 24 * 24 * 512;     // 2,949,120 = NSLOT*512
static constexpr int FBASE = 20480;
static constexpr int WZN   = 4 * 20 * 10 * 10 * 28;  // 224,000
static constexpr int W1SN  = 2 * 4 * 20 * 4 * 128 * 32; // 2,621,440 ushorts
static constexpr int XBT   = 24 * 4 * 512 * 32;      // per-parity xb elems

using bf16x8 = __attribute__((ext_vector_type(8))) short;  // 4 VGPRs
using f32x4  = __attribute__((ext_vector_type(4))) float;

__device__ __forceinline__ unsigned short f2bf(float f) {  // RNE float->bf16
  unsigned u = __float_as_uint(f);
  u += 0x7fff + ((u >> 16) & 1);
  return (unsigned short)(u >> 16);
}
__device__ __forceinline__ float bf2f(unsigned short h) {
  return __uint_as_float((unsigned)h << 16);
}

__device__ __forceinline__ void gload16(const void* g, void* l) {
  __builtin_amdgcn_global_load_lds(
      (const __attribute__((address_space(1))) unsigned int*)g,
      (__attribute__((address_space(3))) unsigned int*)l, 16, 0, 0);
}

// -- kernel 1: x[b][ix][y][t] -> xb{E,O}_{hi,lo}[p][y][ks][b][kk] (k-sliced) --
__global__ __launch_bounds__(256) void k_xbt(const float* __restrict__ x,
                                             unsigned short* __restrict__ xbh,
                                             unsigned short* __restrict__ xbl) {
  __shared__ float lds[64][241];
  const int ix = blockIdx.x;               // 0..23
  const int b0 = blockIdx.y * 64;
  const int tid = threadIdx.x;
  const int p = ix & 1;                    // parity table
  const int c0 = (ix >> 1) * 10;           // column base within table
  #pragma unroll 4
  for (int i = 0; i < 60; ++i) {
    int idx = i * 256 + tid;
    int yt = idx % 240, lb = idx / 240;    // contiguous reads
    lds[lb][yt] = x[(size_t)(b0 + lb) * 5760 + ix * 240 + yt];
  }
  __syncthreads();
  #pragma unroll
  for (int i = 0; i < 6; ++i) {
    int q = i * 256 + tid;
    int lb = q & 63, y = q >> 6;           // y in [0,24)
    const int b = b0 + lb;
    const float* src = &lds[lb][y * 10];
    #pragma unroll
    for (int k0 = 0; k0 < 10; ++k0) {
      const int k = c0 + k0;
      const int ks = k >> 5, kk = k & 31;
      const size_t a = (size_t)p * XBT +
                       (((size_t)(y * 4 + ks) * 512 + b) * 32 + kk);
      float f = src[k0];
      unsigned short hh = f2bf(f);
      xbh[a] = hh;
      xbl[a] = f2bf(f - bf2f(hh));
    }
    if (ix < 2) {                          // zero tail cols 120..127 (k-pad)
      #pragma unroll
      for (int k = 120; k < 128; ++k) {
        const size_t a = (size_t)p * XBT +
                         (((size_t)(y * 4 + 3) * 512 + b) * 32 + (k & 31));
        xbh[a] = 0; xbl[a] = 0;
      }
    }
  }
}

// --- kernel 2: per-(typ,pos) t-bitmaps, prefix offsets, cell metadata ---
__global__ __launch_bounds__(256) void k_meta(const float* __restrict__ mask,
                                              int* __restrict__ bitmap,
                                              int* __restrict__ off,
                                              int* __restrict__ basep,
                                              int* __restrict__ cellmeta,
                                              float* __restrict__ mval) {
  __shared__ int tot[4];
  __shared__ int sb[4];
  const int tid = threadIdx.x;
  const int typ = tid >> 6, lane = tid & 63;       // one wave per typ
  int running = 0;
  for (int c = 0; c < 9; ++c) {                    // 9*64 = 576 positions
    const int pos = c * 64 + lane;
    int mb = 0;
    #pragma unroll
    for (int t = 0; t < 10; ++t)
      if (mask[typ * 5760 + t * 576 + pos] != 0.0f) mb |= (1 << t);
    bitmap[typ * 576 + pos] = mb;
    const int cnt = __popc(mb);
    int s = cnt;                                   // inclusive wave scan
    #pragma unroll
    for (int o = 1; o < 64; o <<= 1) {
      int v = __shfl_up(s, o, 64);
      if (lane >= o) s += v;
    }
    off[typ * 576 + pos] = running + s - cnt;      // exclusive, within typ
    running += __shfl(s, 63, 64);
  }
  if (lane == 63) tot[typ] = running;
  __syncthreads();
  if (tid == 0) {
    int a = 0;
    for (int q = 0; q < 4; ++q) { basep[q] = a; sb[q] = a; a += tot[q]; }
  }
  __syncthreads();
  for (int c = 0; c < 9; ++c) {
    const int pos = c * 64 + lane;
    const int mb = bitmap[typ * 576 + pos];
    int o = sb[typ] + off[typ * 576 + pos];
    const int ex = pos % 24;
    #pragma unroll
    for (int tp = 0; tp < 10; ++tp)
      if ((mb >> tp) & 1) {
        cellmeta[o] = tp * 280 + ex;
        mval[o] = mask[typ * 5760 + tp * 576 + pos];
        ++o;
      }
  }
}

// ---- kernel 2b: wz[typ][ky][tp][ot][c] zero-padded conv2 weights ----
__global__ __launch_bounds__(256) void k_wz(const float* __restrict__ w2,
                                            float* __restrict__ wz) {
  int idx = blockIdx.x * 256 + threadIdx.x;
  if (idx >= WZN) return;
  int c = idx % 28; int r = idx / 28;
  int ot = r % 10; r /= 10;
  int tp = r % 10; r /= 10;
  int ky = r % 20; int typ = r / 20;
  int kt = tp - ot + 7;
  float v = 0.0f;
  if (kt >= 0 && kt < 10 && c >= 3 && c <= 22)
    v = w2[typ * 4000 + kt * 400 + ky * 20 + (c - 3)];
  wz[idx] = v;
}

// -- kernel 2c: w1s_{hi,lo}[h][typ][ky][ks][r][kk] k-sliced im2col tables --
// h=0: ox odd, xx even; h=1: ox even, xx odd. r=(ox>>1)*10+ot, k=(xx>>1)*10+t
__global__ __launch_bounds__(256) void k_w1m(const float* __restrict__ w1,
                                             unsigned short* __restrict__ w1mh,
                                             unsigned short* __restrict__ w1ml) {
  int idx = blockIdx.x * 256 + threadIdx.x;
  if (idx >= W1SN) return;
  int kk = idx & 31;
  int r = (idx >> 5) & 127;
  int rest = idx >> 12;
  int ks = rest & 3; rest >>= 2;
  int ky = rest % 20; rest /= 20;
  int typ = rest % 4; int h = rest / 4;
  int c = ks * 32 + kk;
  float v = 0.0f;
  if (r < 120 && c < 120) {
    int ox = 2 * (r / 10) + (h == 0 ? 1 : 0);
    int ot = r % 10;
    int xx = 2 * (c / 10) + (h == 0 ? 0 : 1);
    int t  = c % 10;
    int sx = xx - ox + 19;                 // even by parity construction
    int kt = t - ot + 7;
    if (sx >= 0 && sx <= 38 && (unsigned)kt <= 9u)
      v = w1[typ * 4000 + kt * 400 + ky * 20 + (sx >> 1)];
  }
  unsigned short h16 = f2bf(v);
  w1mh[idx] = h16;
  w1ml[idx] = f2bf(v - bf2f(h16));
}

// -- kernel 3: conv1 MFMA, m97-style: global_load_lds dbuf staging, 1 h/block
// r31: 3-product split (al*bl dropped; second-order ~2^-16 term).
__global__ __launch_bounds__(256) void k_conv1m(
    const unsigned short* __restrict__ xbh,   // [2][24][4][512][32]
    const unsigned short* __restrict__ xbl,
    const unsigned short* __restrict__ w1mh,  // [2][4][20][4][128][32]
    const unsigned short* __restrict__ w1ml,
    const int* __restrict__ bitmap, const int* __restrict__ off,
    const int* __restrict__ basep, const float* __restrict__ mval,
    float* __restrict__ h1c) {
  __shared__ unsigned short lds[2][12288];   // 2 x 24 KiB
  const int lin = blockIdx.x;                // 0..1535
  const int cx = lin & 7;                    // XCD (round-robin assumed)
  const int typ = cx >> 1, half = cx & 1;
  const int i = lin >> 3;                    // 0..191
  const int n0 = (i & 7) * 64;               // n-strip innermost
  const int rest = i >> 3;                   // 0..23
  const int h = rest & 1;                    // parity half: 0=odd-ox, 1=even
  const int oy = half * 12 + (rest >> 1);
  const int w = threadIdx.x >> 6;            // wave 0..3 -> M tiles w*2,w*2+1
  const int lane = threadIdx.x & 63;
  const int l15 = lane & 15;
  const int kg = (lane >> 4) * 8;            // k sub-offset within 32

  // valid same-parity yy range: sy = yy-oy+19 in [0,38]
  const int py = (oy + 1) & 1;
  int ylo = oy - 19; if (ylo < 0) ylo = 0;
  ylo += (ylo & 1) ^ py;
  int yhi = oy + 19; if (yhi > 23) yhi = 23;
  yhi -= (yhi & 1) ^ py;
  const int ns = (((yhi - ylo) >> 1) + 1) * 4;   // 4 k-slices per yy

  f32x4 acc[2][4];
  #pragma unroll
  for (int mi = 0; mi < 2; ++mi)
    #pragma unroll
    for (int nt = 0; nt < 4; ++nt) {
      f32x4 z = {0.f, 0.f, 0.f, 0.f};
      acc[mi][nt] = z;
    }

  auto stage = [&](int s, int bufi) {
    const int yy = ylo + ((s >> 2) << 1);
    const int ks = s & 3;
    const int ky = (yy - oy + 19) >> 1;
    const size_t asl = ((size_t)((h * 4 + typ) * 20 + ky) * 4 + ks) << 12;
    const unsigned short* Ah = w1mh + asl;
    const unsigned short* Al = w1ml + asl;
    const size_t bsl = (((size_t)(h * 24 + yy) * 4 + ks) << 14) +
                       (size_t)n0 * 32;
    const unsigned short* Bh = xbh + bsl;
    const unsigned short* Bl = xbl + bsl;
    char* lb = (char*)&lds[bufi][0];
    #pragma unroll
    for (int ia = 0; ia < 2; ++ia) {          // A: 8192 B per table
      const int L = ia * 4096 + w * 1024 + lane * 16;
      const int row = L >> 6;
      const int g = row * 64 + ((((L >> 4) & 3) ^ ((row >> 1) & 3)) << 4);
      gload16((const char*)Ah + g, lb + ia * 4096 + w * 1024);
      gload16((const char*)Al + g, lb + 8192 + ia * 4096 + w * 1024);
    }
    {                                          // B: 4096 B per table
      const int L = w * 1024 + lane * 16;
      const int row = L >> 6;
      const int g = row * 64 + ((((L >> 4) & 3) ^ ((row >> 1) & 3)) << 4);
      gload16((const char*)Bh + g, lb + 16384 + w * 1024);
      gload16((const char*)Bl + g, lb + 20480 + w * 1024);
    }
  };

  stage(0, 0);
  __syncthreads();
  int cur = 0;
  for (int s = 0; s < ns; ++s) {
    if (s + 1 < ns) stage(s + 1, cur ^ 1);     // issue next-slice loads first
    const unsigned short* bufb = &lds[cur][0];
    bf16x8 bhv[4], blv[4];
    #pragma unroll
    for (int nt = 0; nt < 4; ++nt) {
      const int n = nt * 16 + l15;
      const int by = n * 64 + (((kg >> 3) ^ ((n >> 1) & 3)) << 4);
      bhv[nt] = *(const bf16x8*)((const char*)(bufb + 8192) + by);
      blv[nt] = *(const bf16x8*)((const char*)(bufb + 10240) + by);
    }
    #pragma unroll
    for (int mi = 0; mi < 2; ++mi) {
      const int r = (w * 2 + mi) * 16 + l15;
      const int ay = r * 64 + (((kg >> 3) ^ ((r >> 1) & 3)) << 4);
      const bf16x8 ah = *(const bf16x8*)((const char*)bufb + ay);
      const bf16x8 al = *(const bf16x8*)((const char*)(bufb + 4096) + ay);
      #pragma unroll
      for (int nt = 0; nt < 4; ++nt) {
        acc[mi][nt] = __builtin_amdgcn_mfma_f32_16x16x32_bf16(
            ah, blv[nt], acc[mi][nt], 0, 0, 0);
        acc[mi][nt] = __builtin_amdgcn_mfma_f32_16x16x32_bf16(
            al, bhv[nt], acc[mi][nt], 0, 0, 0);
        acc[mi][nt] = __builtin_amdgcn_mfma_f32_16x16x32_bf16(
            ah, bhv[nt], acc[mi][nt], 0, 0, 0);
      }
    }
    __syncthreads();                           // drain staging + ds reads
    cur ^= 1;
  }

  // epilogue: compact write with fused relu * mval -> h1c (final values)
  const int bo = basep[typ];
  #pragma unroll
  for (int mi = 0; mi < 2; ++mi) {
    #pragma unroll
    for (int reg = 0; reg < 4; ++reg) {
      const int r = (w * 2 + mi) * 16 + (lane >> 4) * 4 + reg;
      if (r >= 120) continue;                  // padded rows
      const int ox = 2 * (r / 10) + (h == 0 ? 1 : 0);
      const int ot = r % 10;
      const int pos = oy * 24 + ox;
      const int mb = bitmap[typ * 576 + pos];
      if ((mb >> ot) & 1) {
        const int slot = bo + off[typ * 576 + pos] +
                         __popc(mb & ((1 << ot) - 1));
        const float mv = mval[slot];
        #pragma unroll
        for (int nt = 0; nt < 4; ++nt)
          h1c[(size_t)slot * 512 + n0 + nt * 16 + l15] =
              fmaxf(acc[mi][nt][reg], 0.0f) * mv;
      }
    }
  }
}

// -- kernel 4: conv2 (r26 body, verbatim). Depth-4 slot chunks: 4 cellmeta
// reads + 4 xv loads hoisted before the 4 straight-line FMA blocks; weights
// as SGPR operands. Best-measured conv2 (274us).
__global__ __launch_bounds__(256) void k_conv2(const float* __restrict__ h1c,
                                               const float* __restrict__ wz,
                                               const int* __restrict__ bitmap,
                                               const int* __restrict__ off,
                                               const int* __restrict__ basep,
                                               const int* __restrict__ cellmeta,
                                               float* __restrict__ part) {
  const int lin = blockIdx.x;
  const int cx = lin & 7, i = lin >> 3;
  const int typ = cx >> 1;
  const int oy  = (cx & 1) * 12 + (i % 12);
  const int x12 = i / 12;
  const int tile = x12 >> 1, bh = x12 & 1;
  const int ox0 = tile * 4;
  const int b = bh * 256 + threadIdx.x;
  const int bo = __builtin_amdgcn_readfirstlane(basep[typ]);

  float acc[40];
  #pragma unroll
  for (int i2 = 0; i2 < 40; ++i2) acc[i2] = 0.0f;

  const int ex_lo = ox0 - 10 < 0 ? 0 : ox0 - 10;   // d = ex-ox0+10 in [0,22]
  const int ex_hi = ox0 + 12 > 23 ? 23 : ox0 + 12;
  const int ey0 = oy - 10 < 0 ? 0 : oy - 10;
  const int ey1 = oy + 9 > 23 ? 23 : oy + 9;

  auto fmablock = [&](int meta, float xv, int rbase) {
    const float* wrow = wz + rbase + meta;
    #pragma unroll
    for (int ot = 0; ot < 10; ++ot)
      #pragma unroll
      for (int j = 0; j < 4; ++j)
        acc[ot * 4 + j] = fmaf(wrow[ot * 28 + 3 - j], xv, acc[ot * 4 + j]);
  };

  for (int ey = ey0; ey <= ey1; ++ey) {
    const int ky = ey - oy + 10;
    const int rowb = typ * 576 + ey * 24;
    const int s_lo = bo + __builtin_amdgcn_readfirstlane(off[rowb + ex_lo]);
    const int s_hi = bo + __builtin_amdgcn_readfirstlane(off[rowb + ex_hi]) +
                     __popc(__builtin_amdgcn_readfirstlane(bitmap[rowb + ex_hi]));
    const int rbase = (typ * 20 + ky) * 2800 + 10 - ox0;
    int s = s_lo;
    for (; s + 4 <= s_hi; s += 4) {                // depth-4: hoist meta+xv
      const int m0 = __builtin_amdgcn_readfirstlane(cellmeta[s]);
      const int m1 = __builtin_amdgcn_readfirstlane(cellmeta[s + 1]);
      const int m2 = __builtin_amdgcn_readfirstlane(cellmeta[s + 2]);
      const int m3 = __builtin_amdgcn_readfirstlane(cellmeta[s + 3]);
      const float xv0 = h1c[(size_t)s * 512 + b];
      const float xv1 = h1c[(size_t)(s + 1) * 512 + b];
      const float xv2 = h1c[(size_t)(s + 2) * 512 + b];
      const float xv3 = h1c[(size_t)(s + 3) * 512 + b];
      fmablock(m0, xv0, rbase);
      fmablock(m1, xv1, rbase);
      fmablock(m2, xv2, rbase);
      fmablock(m3, xv3, rbase);
    }
    if (s + 2 <= s_hi) {                           // depth-2
      const int m0 = __builtin_amdgcn_readfirstlane(cellmeta[s]);
      const int m1 = __builtin_amdgcn_readfirstlane(cellmeta[s + 1]);
      const float xv0 = h1c[(size_t)s * 512 + b];
      const float xv1 = h1c[(size_t)(s + 1) * 512 + b];
      fmablock(m0, xv0, rbase);
      fmablock(m1, xv1, rbase);
      s += 2;
    }
    if (s < s_hi) {                                // tail
      const int m0 = __builtin_amdgcn_readfirstlane(cellmeta[s]);
      const float xv0 = h1c[(size_t)s * 512 + b];
      fmablock(m0, xv0, rbase);
    }
  }
  #pragma unroll
  for (int ot = 0; ot < 10; ++ot)
    #pragma unroll
    for (int j = 0; j < 4; ++j)
      part[(size_t)(((typ * 10 + ot) * 24 + oy) * 24 + ox0 + j) * 512 + b] =
          acc[ot * 4 + j];
}

// ------ kernel 5: sum 4 typ-partials + transpose to out[b][x][y][t] ------
__global__ __launch_bounds__(256) void k_reduce(const float* __restrict__ part,
                                                float* __restrict__ out) {
  __shared__ float lds[64][241];
  const int xb = blockIdx.x;
  const int b0 = blockIdx.y * 64;
  const int tid = threadIdx.x;
  #pragma unroll 4
  for (int i = 0; i < 60; ++i) {
    int idx = i * 256 + tid;
    int yt = idx >> 6, lb = idx & 63;
    int y = yt / 10, t = yt % 10;
    size_t a = (size_t)((t * 24 + y) * 24 + xb) * 512 + b0 + lb;
    lds[lb][yt] = part[a] + part[a + P] + part[a + 2 * (size_t)P] +
                  part[a + 3 * (size_t)P];
  }
  __syncthreads();
  #pragma unroll 4
  for (int i = 0; i < 60; ++i) {
    int idx = i * 256 + tid;
    int yt = idx % 240, lb = idx / 240;
    out[(size_t)(b0 + lb) * 5760 + xb * 240 + yt] = lds[lb][yt];
  }
}

extern "C" void kernel_launch(void* const* d_in, const int* in_sizes, int n_in,
                              void* d_out, int out_size, void* d_ws, size_t ws_size,
                              hipStream_t stream) {
  const float* x    = (const float*)d_in[0];
  const float* w1   = (const float*)d_in[1];
  const float* w2   = (const float*)d_in[2];
  const float* mask = (const float*)d_in[3];
  float* out = (float*)d_out;
  float* wsf = (float*)d_ws;

  int* bitmap   = (int*)d_ws;
  int* off      = bitmap + 2304;
  int* basep    = bitmap + 4608;
  int* cellmeta = bitmap + 5120;
  float* mval   = wsf + 14336;
  float* part = wsf + FBASE;                             // conv2 out
  unsigned short* xbh  = (unsigned short*)(wsf + FBASE);               // conv1
  unsigned short* xbl  = (unsigned short*)(wsf + FBASE + 1572864);     // conv1
  unsigned short* w1mh = (unsigned short*)(wsf + FBASE + 3145728);     // conv1
  unsigned short* w1ml = (unsigned short*)(wsf + FBASE + 4456448);     // conv1
  float* h1c = wsf + FBASE + (size_t)4 * P;
  float* wz  = wsf + FBASE + (size_t)5 * P;

  k_meta<<<1, 256, 0, stream>>>(mask, bitmap, off, basep, cellmeta, mval);
  k_wz<<<(WZN + 255) / 256, 256, 0, stream>>>(w2, wz);
  k_w1m<<<(W1SN + 255) / 256, 256, 0, stream>>>(w1, w1mh, w1ml);
  k_xbt<<<dim3(24, 8), 256, 0, stream>>>(x, xbh, xbl);
  k_conv1m<<<1536, 256, 0, stream>>>(xbh, xbl, w1mh, w1ml,
                                     bitmap, off, basep, mval, h1c);
  k_conv2<<<1152, 256, 0, stream>>>(h1c, wz, bitmap, off, basep,
                                    cellmeta, part);
  k_reduce<<<dim3(24, 8), 256, 0, stream>>>(part, out);
}